// Round 4
// baseline (273.204 us; speedup 1.0000x reference)
//
#include <hip/hip_runtime.h>

#define FLOOR_EPS 1e-6f

constexpr int Bn  = 64;
constexpr int Tn  = 4096;
constexpr int Cn  = 80;
constexpr int G   = Cn / 4;     // 20 float4 channel-groups per row
constexpr int SEG = 16;         // timesteps per thread
constexpr int NT  = Tn / SEG;   // 256 threads per block

// One block per (batch, channel-group) column. Exact EMA via weighted
// Hillis-Steele scan over per-thread 16-step segment summaries:
//   segment map: s_out = dcy^16 * s_in + B_i   (A uniform per channel!)
// Thread 0 folds the reference's init (a_0 = x_0) into B_0.
__global__ __launch_bounds__(NT, 4)
void pcen_scan_kernel(const float* __restrict__ x,
                      const float* __restrict__ alpha,
                      const float* __restrict__ delta,
                      const float* __restrict__ root,
                      const float* __restrict__ smooth,
                      float* __restrict__ out) {
    __shared__ float4 sc[2][NT];

    const int i = threadIdx.x;
    const int g = blockIdx.x % G;
    const int b = blockIdx.x / G;

    // per-channel params (4 channels per thread)
    float4 smv = ((const float4*)smooth)[g];
    float4 alv = ((const float4*)alpha)[g];
    float4 rov = ((const float4*)root)[g];
    float4 dlv = ((const float4*)delta)[g];
    float w[4], dcy[4], nega[4], invr[4], dl[4], sub[4], A16[4];
    {
        float ws[4] = {smv.x, smv.y, smv.z, smv.w};
        float as[4] = {alv.x, alv.y, alv.z, alv.w};
        float rs[4] = {rov.x, rov.y, rov.z, rov.w};
        dl[0]=dlv.x; dl[1]=dlv.y; dl[2]=dlv.z; dl[3]=dlv.w;
        #pragma unroll
        for (int j = 0; j < 4; ++j) {
            w[j]    = fminf(fmaxf(ws[j], 0.0f), 1.0f);
            dcy[j]  = 1.0f - w[j];
            nega[j] = -fminf(as[j], 1.0f);
            invr[j] = 1.0f / fmaxf(rs[j], 1.0f);
            sub[j]  = __expf(invr[j] * __logf(dl[j]));   // delta^(1/r)
            float d2 = dcy[j] * dcy[j];
            float d4 = d2 * d2;
            float d8 = d4 * d4;
            A16[j]   = d8 * d8;                          // dcy^16
        }
    }
    bool all_sqrt = (invr[0] == 0.5f) & (invr[1] == 0.5f) &
                    (invr[2] == 0.5f) & (invr[3] == 0.5f);

    // ---- phase 1: load my 16 steps (all independent -> deep MLP), local EMA ----
    const size_t base = ((size_t)b * Tn + (size_t)i * SEG) * G + g;
    const float4* px = (const float4*)x + base;
    float4 xs[SEG];
    #pragma unroll
    for (int u = 0; u < SEG; ++u) xs[u] = px[(size_t)u * G];

    float e0, e1, e2, e3;
    if (i == 0) { e0 = xs[0].x; e1 = xs[0].y; e2 = xs[0].z; e3 = xs[0].w; }
    else        { e0 = 0.0f; e1 = 0.0f; e2 = 0.0f; e3 = 0.0f; }
    #pragma unroll
    for (int u = 0; u < SEG; ++u) {
        e0 = fmaf(dcy[0], e0, w[0] * xs[u].x);
        e1 = fmaf(dcy[1], e1, w[1] * xs[u].y);
        e2 = fmaf(dcy[2], e2, w[2] * xs[u].z);
        e3 = fmaf(dcy[3], e3, w[3] * xs[u].w);
    }
    // (thread 0: first step gives dcy*x0 + w*x0 = x0 — exact folded init)

    // ---- phase 2: weighted inclusive scan over 256 segment summaries ----
    sc[0][i] = make_float4(e0, e1, e2, e3);
    __syncthreads();
    float W0 = A16[0], W1 = A16[1], W2 = A16[2], W3 = A16[3];
    int src = 0;
    #pragma unroll
    for (int off = 1; off < NT; off <<= 1) {
        float4 v = sc[src][i];
        if (i >= off) {
            float4 u = sc[src][i - off];
            v.x = fmaf(W0, u.x, v.x);
            v.y = fmaf(W1, u.y, v.y);
            v.z = fmaf(W2, u.z, v.z);
            v.w = fmaf(W3, u.w, v.w);
        }
        sc[src ^ 1][i] = v;
        __syncthreads();
        src ^= 1;
        W0 *= W0; W1 *= W1; W2 *= W2; W3 *= W3;
    }

    // incoming state for my segment = inclusive scan of previous thread
    float m0, m1, m2, m3;
    if (i == 0) { m0 = xs[0].x; m1 = xs[0].y; m2 = xs[0].z; m3 = xs[0].w; }
    else {
        float4 s = sc[src][i - 1];
        m0 = s.x; m1 = s.y; m2 = s.z; m3 = s.w;
    }

    // ---- phase 3: replay 16 steps from scanned state, pointwise PCEN, store ----
    float4* po = (float4*)out + base;
    if (all_sqrt) {          // root == 2 fast path (wave-uniform)
        #pragma unroll
        for (int u = 0; u < SEG; ++u) {
            float4 xv = xs[u];
            m0 = fmaf(dcy[0], m0, w[0] * xv.x);
            m1 = fmaf(dcy[1], m1, w[1] * xv.y);
            m2 = fmaf(dcy[2], m2, w[2] * xv.z);
            m3 = fmaf(dcy[3], m3, w[3] * xv.w);
            float4 ov;
            ov.x = sqrtf(fmaf(xv.x, __expf(nega[0] * __logf(FLOOR_EPS + m0)), dl[0])) - sub[0];
            ov.y = sqrtf(fmaf(xv.y, __expf(nega[1] * __logf(FLOOR_EPS + m1)), dl[1])) - sub[1];
            ov.z = sqrtf(fmaf(xv.z, __expf(nega[2] * __logf(FLOOR_EPS + m2)), dl[2])) - sub[2];
            ov.w = sqrtf(fmaf(xv.w, __expf(nega[3] * __logf(FLOOR_EPS + m3)), dl[3])) - sub[3];
            po[(size_t)u * G] = ov;
        }
    } else {
        #pragma unroll
        for (int u = 0; u < SEG; ++u) {
            float4 xv = xs[u];
            float xv4[4] = {xv.x, xv.y, xv.z, xv.w};
            float mm[4]  = {m0, m1, m2, m3};
            float os[4];
            #pragma unroll
            for (int j = 0; j < 4; ++j) {
                mm[j]   = fmaf(dcy[j], mm[j], w[j] * xv4[j]);
                float p = __expf(nega[j] * __logf(FLOOR_EPS + mm[j]));
                float v = fmaf(xv4[j], p, dl[j]);
                os[j]   = __expf(invr[j] * __logf(v)) - sub[j];
            }
            m0 = mm[0]; m1 = mm[1]; m2 = mm[2]; m3 = mm[3];
            po[(size_t)u * G] = make_float4(os[0], os[1], os[2], os[3]);
        }
    }
}

extern "C" void kernel_launch(void* const* d_in, const int* in_sizes, int n_in,
                              void* d_out, int out_size, void* d_ws, size_t ws_size,
                              hipStream_t stream) {
    const float* x      = (const float*)d_in[0];
    const float* alpha  = (const float*)d_in[1];
    const float* delta  = (const float*)d_in[2];
    const float* root   = (const float*)d_in[3];
    const float* smooth = (const float*)d_in[4];
    float* out = (float*)d_out;

    int grid = Bn * G;   // 1280 blocks x 256 threads = 5120 waves = 20 waves/CU
    pcen_scan_kernel<<<grid, NT, 0, stream>>>(x, alpha, delta, root, smooth, out);
}

// Round 5
// 183.915 us; speedup vs baseline: 1.4855x; 1.4855x over previous
//
#include <hip/hip_runtime.h>

#define FLOOR_EPS 1e-6f

constexpr int Bn    = 64;
constexpr int Tn    = 4096;
constexpr int Cn    = 80;
constexpr int G     = Cn / 4;       // 20 float4 channel-groups per row
constexpr int CHUNK = 32;           // timesteps per thread
constexpr int NCH   = Tn / CHUNK;   // 128 chunks per row
constexpr int TOT   = Bn * NCH * G; // 163,840 threads (A and B)

// ---------------- Kernel A: exact per-chunk EMA summaries ----------------
// tid = (b*NCH + k)*G + g  (g fastest -> coalesced, 4 lanes per 64B line).
// Chunk summary: state_after = dcy^CHUNK * state_before + Bk, where Bk is the
// local EMA started from 0 (k>0) or from the exact folded init x0 (k==0).
__global__ __launch_bounds__(256)
void pcen_sum_kernel(const float* __restrict__ x,
                     const float* __restrict__ smooth,
                     float4* __restrict__ ws_sum) {
    int tid = blockIdx.x * blockDim.x + threadIdx.x;
    if (tid >= TOT) return;
    int g = tid % G;
    int k = (tid / G) % NCH;
    int b = tid / (G * NCH);

    float4 smv = ((const float4*)smooth)[g];
    float w0 = fminf(fmaxf(smv.x, 0.f), 1.f), w1 = fminf(fmaxf(smv.y, 0.f), 1.f);
    float w2 = fminf(fmaxf(smv.z, 0.f), 1.f), w3 = fminf(fmaxf(smv.w, 0.f), 1.f);
    float d0 = 1.f - w0, d1 = 1.f - w1, d2 = 1.f - w2, d3 = 1.f - w3;

    const float4* px = (const float4*)x + ((size_t)b * Tn + (size_t)k * CHUNK) * G + g;
    float4 xs[CHUNK];
    #pragma unroll
    for (int u = 0; u < CHUNK; ++u) xs[u] = px[(size_t)u * G];   // 32 independent loads

    float e0, e1, e2, e3;
    if (k == 0) { e0 = xs[0].x; e1 = xs[0].y; e2 = xs[0].z; e3 = xs[0].w; }
    else        { e0 = 0.f; e1 = 0.f; e2 = 0.f; e3 = 0.f; }
    #pragma unroll
    for (int u = 0; u < CHUNK; ++u) {
        e0 = fmaf(d0, e0, w0 * xs[u].x);
        e1 = fmaf(d1, e1, w1 * xs[u].y);
        e2 = fmaf(d2, e2, w2 * xs[u].z);
        e3 = fmaf(d3, e3, w3 * xs[u].w);
    }
    ws_sum[tid] = make_float4(e0, e1, e2, e3);   // tid == (b*NCH+k)*G+g
}

// ---------------- Kernel C: in-place weighted scan over chunk summaries ----
// One block per (b,g); 128 threads = 128 chunks. inclusive[k] = true EMA state
// after chunk k. Weight A = dcy^CHUNK, squared each Hillis-Steele round.
__global__ __launch_bounds__(NCH)
void pcen_chunkscan_kernel(const float* __restrict__ smooth,
                           float4* __restrict__ ws_sum) {
    __shared__ float4 sc[2][NCH];
    const int k = threadIdx.x;
    const int g = blockIdx.x % G;
    const int b = blockIdx.x / G;

    float4 smv = ((const float4*)smooth)[g];
    float W[4];
    {
        float ws4[4] = {smv.x, smv.y, smv.z, smv.w};
        #pragma unroll
        for (int j = 0; j < 4; ++j) {
            float d = 1.f - fminf(fmaxf(ws4[j], 0.f), 1.f);
            float d2 = d * d, d4 = d2 * d2, d8 = d4 * d4, d16 = d8 * d8;
            W[j] = d16 * d16;                      // dcy^32
        }
    }

    const size_t idx = ((size_t)b * NCH + k) * G + g;
    sc[0][k] = ws_sum[idx];
    __syncthreads();
    int src = 0;
    float W0 = W[0], W1 = W[1], W2 = W[2], W3 = W[3];
    #pragma unroll
    for (int off = 1; off < NCH; off <<= 1) {
        float4 v = sc[src][k];
        if (k >= off) {
            float4 u = sc[src][k - off];
            v.x = fmaf(W0, u.x, v.x);
            v.y = fmaf(W1, u.y, v.y);
            v.z = fmaf(W2, u.z, v.z);
            v.w = fmaf(W3, u.w, v.w);
        }
        sc[src ^ 1][k] = v;
        __syncthreads();
        src ^= 1;
        W0 *= W0; W1 *= W1; W2 *= W2; W3 *= W3;
    }
    ws_sum[idx] = sc[src][k];                      // in-place: now inclusive states
}

// ---------------- Kernel B: replay chunks from scanned states + pointwise ----
__global__ __launch_bounds__(256)
void pcen_out_kernel(const float* __restrict__ x,
                     const float* __restrict__ alpha,
                     const float* __restrict__ delta,
                     const float* __restrict__ root,
                     const float* __restrict__ smooth,
                     const float4* __restrict__ ws_scan,
                     float* __restrict__ out) {
    int tid = blockIdx.x * blockDim.x + threadIdx.x;
    if (tid >= TOT) return;
    int g = tid % G;
    int k = (tid / G) % NCH;
    int b = tid / (G * NCH);

    float4 smv = ((const float4*)smooth)[g];
    float4 alv = ((const float4*)alpha)[g];
    float4 rov = ((const float4*)root)[g];
    float4 dlv = ((const float4*)delta)[g];
    float w[4], dcy[4], nega[4], invr[4], dl[4], sub[4];
    {
        float ws4[4] = {smv.x, smv.y, smv.z, smv.w};
        float as[4]  = {alv.x, alv.y, alv.z, alv.w};
        float rs[4]  = {rov.x, rov.y, rov.z, rov.w};
        dl[0]=dlv.x; dl[1]=dlv.y; dl[2]=dlv.z; dl[3]=dlv.w;
        #pragma unroll
        for (int j = 0; j < 4; ++j) {
            w[j]    = fminf(fmaxf(ws4[j], 0.f), 1.f);
            dcy[j]  = 1.f - w[j];
            nega[j] = -fminf(as[j], 1.f);
            invr[j] = 1.f / fmaxf(rs[j], 1.f);
            sub[j]  = __expf(invr[j] * __logf(dl[j]));   // delta^(1/r)
        }
    }
    bool all_sqrt = (invr[0] == 0.5f) & (invr[1] == 0.5f) &
                    (invr[2] == 0.5f) & (invr[3] == 0.5f);

    const float4* px = (const float4*)x + ((size_t)b * Tn + (size_t)k * CHUNK) * G + g;
    float4* po = (float4*)out + ((size_t)b * Tn + (size_t)k * CHUNK) * G + g;

    // incoming state: inclusive scan of previous chunk (coalesced: tid - G)
    float m0, m1, m2, m3;
    float4 xs[CHUNK];
    if (k > 0) {
        float4 s = ws_scan[tid - G];
        #pragma unroll
        for (int u = 0; u < CHUNK; ++u) xs[u] = px[(size_t)u * G];
        m0 = s.x; m1 = s.y; m2 = s.z; m3 = s.w;
    } else {
        #pragma unroll
        for (int u = 0; u < CHUNK; ++u) xs[u] = px[(size_t)u * G];
        m0 = xs[0].x; m1 = xs[0].y; m2 = xs[0].z; m3 = xs[0].w;  // exact folded init
    }

    if (all_sqrt) {      // root == 2 fast path (wave-uniform)
        #pragma unroll
        for (int u = 0; u < CHUNK; ++u) {
            float4 xv = xs[u];
            m0 = fmaf(dcy[0], m0, w[0] * xv.x);
            m1 = fmaf(dcy[1], m1, w[1] * xv.y);
            m2 = fmaf(dcy[2], m2, w[2] * xv.z);
            m3 = fmaf(dcy[3], m3, w[3] * xv.w);
            float4 ov;
            ov.x = sqrtf(fmaf(xv.x, __expf(nega[0] * __logf(FLOOR_EPS + m0)), dl[0])) - sub[0];
            ov.y = sqrtf(fmaf(xv.y, __expf(nega[1] * __logf(FLOOR_EPS + m1)), dl[1])) - sub[1];
            ov.z = sqrtf(fmaf(xv.z, __expf(nega[2] * __logf(FLOOR_EPS + m2)), dl[2])) - sub[2];
            ov.w = sqrtf(fmaf(xv.w, __expf(nega[3] * __logf(FLOOR_EPS + m3)), dl[3])) - sub[3];
            po[(size_t)u * G] = ov;
        }
    } else {
        #pragma unroll
        for (int u = 0; u < CHUNK; ++u) {
            float4 xv = xs[u];
            float xv4[4] = {xv.x, xv.y, xv.z, xv.w};
            float mm[4]  = {m0, m1, m2, m3};
            float os[4];
            #pragma unroll
            for (int j = 0; j < 4; ++j) {
                mm[j]   = fmaf(dcy[j], mm[j], w[j] * xv4[j]);
                float p = __expf(nega[j] * __logf(FLOOR_EPS + mm[j]));
                float v = fmaf(xv4[j], p, dl[j]);
                os[j]   = __expf(invr[j] * __logf(v)) - sub[j];
            }
            m0 = mm[0]; m1 = mm[1]; m2 = mm[2]; m3 = mm[3];
            po[(size_t)u * G] = make_float4(os[0], os[1], os[2], os[3]);
        }
    }
}

extern "C" void kernel_launch(void* const* d_in, const int* in_sizes, int n_in,
                              void* d_out, int out_size, void* d_ws, size_t ws_size,
                              hipStream_t stream) {
    const float* x      = (const float*)d_in[0];
    const float* alpha  = (const float*)d_in[1];
    const float* delta  = (const float*)d_in[2];
    const float* root   = (const float*)d_in[3];
    const float* smooth = (const float*)d_in[4];
    float* out = (float*)d_out;

    float4* ws_sum = (float4*)d_ws;    // TOT float4 = 2.62 MB (in-place scanned)

    int block = 256;
    int gridA = (TOT + block - 1) / block;                 // 640 blocks
    pcen_sum_kernel<<<gridA, block, 0, stream>>>(x, smooth, ws_sum);
    pcen_chunkscan_kernel<<<Bn * G, NCH, 0, stream>>>(smooth, ws_sum);  // 1280 x 128
    pcen_out_kernel<<<gridA, block, 0, stream>>>(x, alpha, delta, root, smooth,
                                                 ws_sum, out);
}